// Round 5
// baseline (404.960 us; speedup 1.0000x reference)
//
#include <hip/hip_runtime.h>
#include <math.h>

// VQ-VAE quantize: z [32,8,16,16] f32, codebook [16384,8] f32
// N=8192 rows, K=16384 codes, D=8.
// Outputs (concatenated f32): z_q [65536], loss [1], idx-as-float [8192].
//
// f[n,k] = 200*dot(z_n,e_k) - 100*||e_k||^2 (softmax/argmax shift-invariant;
// T=0.01). exp underflows for f-m < -87 (validated vs fp32 ref, R2-R4).
//
// R4 lesson: 256 blocks x 53KB LDS = 1 wave/SIMD -> every ds_read/barrier/
// atomic latency fully exposed (1360 cyc/j-iter vs ~165 VALU). Now K-split:
// 1024 blocks (4 slices x 256 row-groups), 37KB LDS -> 4 blocks/CU.
// pass1 records candidates (k,f) per row to global; rowfix (1 wave/row)
// computes softmax stats/argmin/entropy/avgp/zq from the few candidates.

#define KCODES 16384
#define TILE   512
#define SLICE_TILES 8          // 4096 codes per slice
#define ROWCAP 48

__device__ __forceinline__ float dot8v(const float* zr, float4 L, float4 H,
                                       float b) {
    float a = fmaf(zr[0], L.x, b);
    a = fmaf(zr[1], L.y, a);
    a = fmaf(zr[2], L.z, a);
    a = fmaf(zr[3], L.w, a);
    a = fmaf(zr[4], H.x, a);
    a = fmaf(zr[5], H.y, a);
    a = fmaf(zr[6], H.z, a);
    a = fmaf(zr[7], H.w, a);
    return a;
}
__device__ __forceinline__ float norm8(float4 L, float4 H) {
    return L.x * L.x + L.y * L.y + L.z * L.z + L.w * L.w
         + H.x * H.x + H.y * H.y + H.z * H.z + H.w * H.w;
}
// order-preserving float<->int for LDS atomicMax (no NaNs here)
__device__ __forceinline__ int encf(float f) {
    int i = __float_as_int(f);
    return i < 0 ? (i ^ 0x7fffffff) : i;
}
__device__ __forceinline__ float decf(int i) {
    return __int_as_float(i < 0 ? (i ^ 0x7fffffff) : i);
}

// ---------------- pass 1: K-split sweep, candidate recording ----------------
__global__ __launch_bounds__(256, 4) void pass1(
    const float* __restrict__ z, const float* __restrict__ cb,
    int* __restrict__ gcnt, float2* __restrict__ grec)
{
    __shared__ float4 lo[2][TILE];
    __shared__ float4 hi[2][TILE];
    __shared__ float  bkt[2][TILE];
    __shared__ int    mI[32];          // per-block-row running max (encoded)

    const int tid  = threadIdx.x;
    const int wave = tid >> 6;
    const int lane = tid & 63;
    const int wrow0 = wave * 8;
    const int rowgrp = blockIdx.x >> 2;
    const int slice  = blockIdx.x & 3;
    const int growbase = rowgrp * 32;
    const int kbase = slice * (TILE * SLICE_TILES);

    // this wave's 8 rows, 200x scale folded (wave-uniform -> scalarized)
    float za[8][8];
#pragma unroll
    for (int r = 0; r < 8; ++r) {
        int row = growbase + wrow0 + r;
        int bb = row >> 8, hw = row & 255;
        const float* p = z + bb * 2048 + hw;
#pragma unroll
        for (int c = 0; c < 8; ++c) za[r][c] = 200.0f * p[c * 256];
    }

    const float4* cbv = (const float4*)cb;
    float4 l0, h0, l1, h1; float b0, b1;
#define STAGE_LD(t)  { int k0 = kbase + (t) * TILE + tid, k1 = k0 + 256;  \
        l0 = cbv[2 * k0]; h0 = cbv[2 * k0 + 1];                           \
        l1 = cbv[2 * k1]; h1 = cbv[2 * k1 + 1];                           \
        b0 = -100.0f * norm8(l0, h0); b1 = -100.0f * norm8(l1, h1); }
#define STAGE_WR(bf) { lo[bf][tid] = l0; hi[bf][tid] = h0;                \
        lo[bf][tid + 256] = l1; hi[bf][tid + 256] = h1;                   \
        bkt[bf][tid] = b0; bkt[bf][tid + 256] = b1; }

    STAGE_LD(0); STAGE_WR(0);
    __syncthreads();

    // warm-up A: exact max over tile 0 (no recording)
    float mt[8];
    {
        float wm[8];
#pragma unroll
        for (int r = 0; r < 8; ++r) wm[r] = -3.4e38f;
#pragma unroll
        for (int j = 0; j < 8; ++j) {
            int ci = j * 64 + lane;
            float4 L = lo[0][ci], H = hi[0][ci];
            float b = bkt[0][ci];
#pragma unroll
            for (int r = 0; r < 8; ++r) wm[r] = fmaxf(wm[r], dot8v(za[r], L, H, b));
        }
#pragma unroll
        for (int r = 0; r < 8; ++r) {
#pragma unroll
            for (int off = 32; off; off >>= 1) wm[r] = fmaxf(wm[r], __shfl_xor(wm[r], off));
            mt[r] = wm[r] - 87.0f;
        }
        if (lane == 0) {
#pragma unroll
            for (int r = 0; r < 8; ++r) mI[wrow0 + r] = encf(wm[r]);
        }
    }

    STAGE_LD(1);   // tile-1 loads in flight under warm-up B

    // warm-up B: re-scan tile 0 with recording
#pragma unroll 2
    for (int j = 0; j < 8; ++j) {
        int ci = j * 64 + lane;
        float4 L = lo[0][ci], H = hi[0][ci];
        float b = bkt[0][ci];
        float fv[8];
#pragma unroll
        for (int r = 0; r < 8; ++r) fv[r] = dot8v(za[r], L, H, b);
        int hh = 0;
#pragma unroll
        for (int r = 0; r < 8; ++r) hh |= (fv[r] > mt[r]);
        if (__any(hh)) {
#pragma unroll
            for (int r = 0; r < 8; ++r) {
                if (fv[r] > mt[r]) {
                    mt[r] = fmaxf(mt[r], fv[r] - 87.0f);
                    atomicMax(&mI[wrow0 + r], encf(fv[r]));
                    int rowg = growbase + wrow0 + r;
                    int pos = atomicAdd(&gcnt[rowg], 1);
                    if (pos < ROWCAP)
                        grec[rowg * ROWCAP + pos] =
                            make_float2(fv[r], __int_as_float(kbase + ci));
                }
            }
        }
    }
    STAGE_WR(1);
    __syncthreads();

    // main sweep: tiles 1..7 of this slice, double-buffered
    for (int t = 1; t < SLICE_TILES; ++t) {
        const int bf = t & 1;
        const int tb = kbase + t * TILE;
        const bool more = (t + 1 < SLICE_TILES);
        if (more) STAGE_LD(t + 1);
#pragma unroll 2
        for (int j = 0; j < 8; ++j) {
            int ci = j * 64 + lane;
            float4 L = lo[bf][ci], H = hi[bf][ci];
            float b = bkt[bf][ci];
            float fv[8];
#pragma unroll
            for (int r = 0; r < 8; ++r) fv[r] = dot8v(za[r], L, H, b);
            int hh = 0;
#pragma unroll
            for (int r = 0; r < 8; ++r) hh |= (fv[r] > mt[r]);
            if (__any(hh)) {
#pragma unroll
                for (int r = 0; r < 8; ++r) {
                    if (fv[r] > mt[r]) {
                        mt[r] = fmaxf(mt[r], fv[r] - 87.0f);
                        atomicMax(&mI[wrow0 + r], encf(fv[r]));
                        int rowg = growbase + wrow0 + r;
                        int pos = atomicAdd(&gcnt[rowg], 1);
                        if (pos < ROWCAP)
                            grec[rowg * ROWCAP + pos] =
                                make_float2(fv[r], __int_as_float(tb + ci));
                    }
                }
            }
        }
        if (t & 1) {   // tighten to block-row running max (cheap ds_reads)
#pragma unroll
            for (int r = 0; r < 8; ++r)
                mt[r] = fmaxf(mt[r], decf(mI[wrow0 + r]) - 87.0f);
        }
        if (more) STAGE_WR((t + 1) & 1);
        __syncthreads();
    }
#undef STAGE_LD
#undef STAGE_WR
}

// ---------------- rowfix: 1 wave per row, merge candidates ----------------
__global__ __launch_bounds__(256) void rowfix(
    const float* __restrict__ z, const float* __restrict__ cb,
    const int* __restrict__ gcnt, const float2* __restrict__ grec,
    float* __restrict__ avgp, float* __restrict__ out_zq,
    float* __restrict__ out_idx, float* __restrict__ scal)
{
    const int wave = threadIdx.x >> 6;
    const int lane = threadIdx.x & 63;
    const int row = blockIdx.x * 4 + wave;
    const float4* cbv = (const float4*)cb;
    const int c = gcnt[row];

    float ent = 0.0f, sq = 0.0f;   // lane-0 carries per-row scalars
    if (c <= ROWCAP) {
        float f = -3.4e38f; int k = 0x7fffffff;
        if (lane < c) {
            float2 rc = grec[row * ROWCAP + lane];
            f = rc.x; k = __float_as_int(rc.y);
        }
        float m = f;
#pragma unroll
        for (int off = 32; off; off >>= 1) m = fmaxf(m, __shfl_xor(m, off));
        float x = f - m;
        float e = (x > -87.0f) ? __expf(x) : 0.0f;   // lane>=c: x<<-87 -> 0
        float s = e, t = x * e;
        int kmin = (e > 0.0f && x == 0.0f) ? k : 0x7fffffff;
#pragma unroll
        for (int off = 32; off; off >>= 1) {
            s += __shfl_xor(s, off);
            t += __shfl_xor(t, off);
            kmin = min(kmin, __shfl_xor(kmin, off));
        }
        float rs = 1.0f / s;
        if (e > 0.0f) atomicAdd(&avgp[k], e * rs);
        if (lane == 0) {
            ent = t * rs - logf(s);
            out_idx[row] = (float)kmin;
            float4 q0 = cbv[2 * kmin], q1 = cbv[2 * kmin + 1];
            float qv[8] = {q0.x, q0.y, q0.z, q0.w, q1.x, q1.y, q1.z, q1.w};
            int bb = row >> 8, hw = row & 255;
            const float* zp = z + bb * 2048 + hw;
            float* o = out_zq + bb * 2048 + hw;
#pragma unroll
            for (int ch = 0; ch < 8; ++ch) {
                float raw = zp[ch * 256];
                o[ch * 256] = qv[ch];
                float dq = qv[ch] - raw;
                sq += dq * dq;
            }
        }
    } else {
        // overflow fallback: exact wave-parallel recompute (rare)
        float zs[8], zraw[8];
        int bb = row >> 8, hw = row & 255;
        const float* zp = z + bb * 2048 + hw;
#pragma unroll
        for (int ch = 0; ch < 8; ++ch) {
            zraw[ch] = zp[ch * 256];
            zs[ch] = 200.0f * zraw[ch];
        }
        float m = -3.4e38f, s = 0.0f, t = 0.0f;
        int kloc = 0x7fffffff;
        for (int k = lane; k < KCODES; k += 64) {
            float4 L = cbv[2 * k], H = cbv[2 * k + 1];
            float f = dot8v(zs, L, H, -100.0f * norm8(L, H));
            float x = f - m;
            if (x > 0.0f) {
                float fsc = __expf(-x);
                t = fsc * fmaf(-x, s, t);
                s = fmaf(s, fsc, 1.0f);
                m = f; kloc = k;
            } else if (x > -87.0f) {
                float e = __expf(x);
                s += e; t = fmaf(x, e, t);
            }
        }
        for (int off = 32; off; off >>= 1) {
            float mo = __shfl_xor(m, off);
            float so = __shfl_xor(s, off);
            float to = __shfl_xor(t, off);
            int   ko = __shfl_xor(kloc, off);
            float mn = fmaxf(m, mo);
            float d1 = m - mn, d2 = mo - mn;
            float f1 = __expf(d1), f2 = __expf(d2);
            t = f1 * fmaf(d1, s, t) + f2 * fmaf(d2, so, to);
            s = f1 * s + f2 * so;
            kloc = (m > mo) ? kloc : ((mo > m) ? ko : (kloc < ko ? kloc : ko));
            m = mn;
        }
        float rs = 1.0f / s;
        for (int k = lane; k < KCODES; k += 64) {
            float4 L = cbv[2 * k], H = cbv[2 * k + 1];
            float f = dot8v(zs, L, H, -100.0f * norm8(L, H));
            float x = f - m;
            if (x > -87.0f) atomicAdd(&avgp[k], __expf(x) * rs);
        }
        if (lane == 0) {
            ent = t * rs - logf(s);
            out_idx[row] = (float)kloc;
            float4 q0 = cbv[2 * kloc], q1 = cbv[2 * kloc + 1];
            float qv[8] = {q0.x, q0.y, q0.z, q0.w, q1.x, q1.y, q1.z, q1.w};
            float* o = out_zq + bb * 2048 + hw;
#pragma unroll
            for (int ch = 0; ch < 8; ++ch) {
                o[ch * 256] = qv[ch];
                float dq = qv[ch] - zraw[ch];
                sq += dq * dq;
            }
        }
    }
    // block reduce (4 per-row scalars) -> 2 atomics
    __shared__ float redSq[4], redEnt[4];
    if (lane == 0) { redSq[wave] = sq; redEnt[wave] = ent; }
    __syncthreads();
    if (threadIdx.x == 0) {
        atomicAdd(&scal[0], redSq[0] + redSq[1] + redSq[2] + redSq[3]);
        atomicAdd(&scal[1], redEnt[0] + redEnt[1] + redEnt[2] + redEnt[3]);
    }
}

// ---------------- finalize: avg entropy + loss assembly ----------------
__global__ __launch_bounds__(256) void finalize(
    const float* __restrict__ avgp, const float* __restrict__ scal,
    float* __restrict__ out_loss)
{
    float acc = 0.0f;
    for (int k = threadIdx.x; k < KCODES; k += 256) {
        float avg = avgp[k] * (1.0f / 8192.0f);
        acc += avg * logf(avg + 1e-5f);    // avg==0 contributes exactly 0
    }
#pragma unroll
    for (int off = 32; off > 0; off >>= 1) acc += __shfl_xor(acc, off);
    __shared__ float red[4];
    int wave = threadIdx.x >> 6, lane = threadIdx.x & 63;
    if (lane == 0) red[wave] = acc;
    __syncthreads();
    if (threadIdx.x == 0) {
        float T = red[0] + red[1] + red[2] + red[3];   // sum avg*log(avg+eps)
        // loss = 1.25*mean((zq-z)^2) + 0.1*(sample_entropy - avg_entropy)
        float loss = 1.25f * (scal[0] * (1.0f / 65536.0f))
                   + 0.1f * (T - scal[1] * (1.0f / 8192.0f));
        out_loss[0] = loss;
    }
}

extern "C" void kernel_launch(void* const* d_in, const int* in_sizes, int n_in,
                              void* d_out, int out_size, void* d_ws, size_t ws_size,
                              hipStream_t stream) {
    const float* z  = (const float*)d_in[0];   // [32,8,16,16]
    const float* cb = (const float*)d_in[1];   // [16384,8]
    float* out = (float*)d_out;
    float* ws  = (float*)d_ws;

    // workspace layout (floats)
    float*  avgp = ws;                       // 16384 : sum_n p[n,k]
    float*  scal = ws + 16384;               // 2 (+6 pad)
    int*    gcnt = (int*)(ws + 16392);       // 8192  : per-row candidate count
    float2* grec = (float2*)(ws + 24584);    // 8192*48 float2 = 3.0 MB

    float* out_zq   = out;           // 65536
    float* out_loss = out + 65536;   // 1
    float* out_idx  = out + 65537;   // 8192

    // zero avgp + scal + gcnt (ws is re-poisoned to 0xAA every launch)
    hipMemsetAsync(ws, 0, (16384 + 8 + 8192) * sizeof(float), stream);

    pass1   <<<1024, 256, 0, stream>>>(z, cb, gcnt, grec);
    rowfix  <<<2048, 256, 0, stream>>>(z, cb, gcnt, grec, avgp, out_zq,
                                       out_idx, scal);
    finalize<<<1,    256, 0, stream>>>(avgp, scal, out_loss);
}